// Round 3
// baseline (548.464 us; speedup 1.0000x reference)
//
#include <hip/hip_runtime.h>
#include <hip/hip_bf16.h>

typedef unsigned short ush;

__device__ __forceinline__ float sigf(float x) {
  return __fdividef(1.0f, 1.0f + __expf(-x));
}
__device__ __forceinline__ float tanhfast(float x) {
  float e = __expf(2.0f * x);
  return 1.0f - __fdividef(2.0f, e + 1.0f);
}

// ---------------------------------------------------------------------------
// K1: LSTM1 over 4096 sequences (T=10, D=13, H=128). 256 blocks x 512 thr.
// Block b owns cond1 seqs [8b,8b+8) (rows 0..7) and cond2 seqs (rows 8..15).
// Whh1 (f32, 256KB) is restaged from L2 in 16-k-row chunks (32KB LDS).
// Thread (ks = tid&127, p = tid>>7): rows 4p..4p+3, gate cols {ks,128+ks,...}.
// Epilogue: relu(h@Wc+bc) pairs -> lo, BN1 sums via atomics.
// ---------------------------------------------------------------------------
__global__ __launch_bounds__(512, 1) void k_lstm1(
    const float* __restrict__ cond1, const float* __restrict__ cond2,
    const float* __restrict__ Wih1, const float* __restrict__ Whh1,
    const float* __restrict__ b1, const float* __restrict__ Wc,
    const float* __restrict__ bc,
    float* __restrict__ lo_raw, float* __restrict__ gsums)
{
  __shared__ float wS[16][512];   // K-chunk of Whh1, layout [k][col] (32KB)
  __shared__ float hs[16][132];   // h state
  __shared__ float xs[16][130];   // per-seq inputs, 10 steps x 13
  __shared__ float rr[16][64];    // relu(h@Wc+bc)
  __shared__ float sloc[128];     // block-local BN sums

  const int tid = threadIdx.x;
  const int b = blockIdx.x;

  for (int idx = tid; idx < 16 * 130; idx += 512) {
    int r = idx / 130, d = idx - r * 130;
    xs[r][d] = (r < 8) ? cond1[(8 * b + r) * 130 + d]
                       : cond2[(8 * b + (r - 8)) * 130 + d];
  }
  for (int idx = tid; idx < 16 * 132; idx += 512) (&hs[0][0])[idx] = 0.0f;
  if (tid < 128) sloc[tid] = 0.0f;
  __syncthreads();   // xs/hs init visible before first use (t=0 reads xs)

  const int ks = tid & 127;
  const int p = tid >> 7;   // [0,4): rows 4p..4p+3

  float wihv[13][4];
#pragma unroll
  for (int d = 0; d < 13; ++d)
#pragma unroll
    for (int j = 0; j < 4; ++j) wihv[d][j] = Wih1[d * 512 + j * 128 + ks];
  float b1v[4];
#pragma unroll
  for (int j = 0; j < 4; ++j) b1v[j] = b1[j * 128 + ks];

  float creg[4] = {0.f, 0.f, 0.f, 0.f};

  for (int t = 0; t < 10; ++t) {
    float acc[4][4];
#pragma unroll
    for (int j = 0; j < 4; ++j)
#pragma unroll
      for (int r = 0; r < 4; ++r) acc[j][r] = b1v[j];

    // x_t @ Wih1 (weights in regs, x broadcast from LDS)
#pragma unroll
    for (int d = 0; d < 13; ++d) {
#pragma unroll
      for (int r = 0; r < 4; ++r) {
        float xv = xs[4 * p + r][t * 13 + d];
#pragma unroll
        for (int j = 0; j < 4; ++j) acc[j][r] = fmaf(xv, wihv[d][j], acc[j][r]);
      }
    }
    // h @ Whh1, K in chunks of 16 rows staged through LDS
    for (int kc = 0; kc < 128; kc += 16) {
      __syncthreads();   // prior consumers of wS done
      {
        const float4* src = reinterpret_cast<const float4*>(Whh1 + kc * 512);
        float4* dst = reinterpret_cast<float4*>(&wS[0][0]);
        for (int i = tid; i < 2048; i += 512) dst[i] = src[i];
      }
      __syncthreads();
#pragma unroll 4
      for (int kk = 0; kk < 16; ++kk) {
        float w0 = wS[kk][ks];
        float w1 = wS[kk][128 + ks];
        float w2 = wS[kk][256 + ks];
        float w3 = wS[kk][384 + ks];
#pragma unroll
        for (int r = 0; r < 4; ++r) {
          float hv = hs[4 * p + r][kc + kk];
          acc[0][r] = fmaf(hv, w0, acc[0][r]);
          acc[1][r] = fmaf(hv, w1, acc[1][r]);
          acc[2][r] = fmaf(hv, w2, acc[2][r]);
          acc[3][r] = fmaf(hv, w3, acc[3][r]);
        }
      }
    }
    __syncthreads();   // all hs reads done before overwrite
#pragma unroll
    for (int r = 0; r < 4; ++r) {
      float ig = sigf(acc[0][r]);
      float fg = sigf(acc[1][r]);
      float gg = tanhfast(acc[2][r]);
      float og = sigf(acc[3][r]);
      float c = fmaf(fg, creg[r], ig * gg);
      creg[r] = c;
      hs[4 * p + r][ks] = og * tanhfast(c);
    }
    __syncthreads();
  }

  // rr = relu(h_final @ Wc + bc): thread (oc = tid&63, rg = tid>>6) -> 2 rows
  {
    const int oc = tid & 63, rg = tid >> 6;  // rg in [0,8)
    float a0 = bc[oc], a1 = a0;
    for (int k = 0; k < 128; ++k) {
      float wcv = Wc[k * 64 + oc];
      a0 = fmaf(hs[rg * 2 + 0][k], wcv, a0);
      a1 = fmaf(hs[rg * 2 + 1][k], wcv, a1);
    }
    rr[rg * 2 + 0][oc] = fmaxf(a0, 0.0f);
    rr[rg * 2 + 1][oc] = fmaxf(a1, 0.0f);
  }
  __syncthreads();
  {
    const int j = tid >> 6, oc = tid & 63;   // 512 threads = 8 rows x 64 cols
    float lo = 0.5f * (rr[j][oc] + rr[j + 8][oc]);
    lo_raw[(8 * b + j) * 64 + oc] = lo;
    atomicAdd(&sloc[oc], lo);
    atomicAdd(&sloc[64 + oc], lo * lo);
  }
  __syncthreads();
  if (tid < 128) atomicAdd(&gsums[tid], sloc[tid]);
}

// ---------------------------------------------------------------------------
// K2: finalize BN1, build out = concat(ops, extra, card, bn(lo)) as fp32.
// ---------------------------------------------------------------------------
__global__ __launch_bounds__(256) void k_buildout(
    const float* __restrict__ ops, const float* __restrict__ extra,
    const float* __restrict__ card, const float* __restrict__ g1,
    const float* __restrict__ be1, const float* __restrict__ gsums,
    const float* __restrict__ lo_raw, float* __restrict__ outbuf)
{
  __shared__ float av[64], bv[64];
  const int tid = threadIdx.x;
  if (tid < 64) {
    float m = gsums[tid] * (1.0f / 2048.0f);
    float var = gsums[64 + tid] * (1.0f / 2048.0f) - m * m;
    float rstd = rsqrtf(var + 1e-5f);
    float gg = g1[tid];
    av[tid] = rstd * gg;
    bv[tid] = be1[tid] - m * rstd * gg;
  }
  __syncthreads();
  const int g = blockIdx.x * 256 + tid;  // [0,2048) = l*128+n
  const float* lr = lo_raw + g * 64;
  float* o = outbuf + g * 88;
#pragma unroll
  for (int c = 0; c < 15; ++c) o[c] = ops[g * 15 + c];
#pragma unroll
  for (int c = 0; c < 7; ++c) o[15 + c] = extra[g * 7 + c];
  o[22] = card[g * 2 + 0];
  o[23] = card[g * 2 + 1];
  for (int j = 0; j < 64; ++j) o[24 + j] = lr[j] * av[j] + bv[j];
}

// ---------------------------------------------------------------------------
// K3: LSTM2 single step on out[15] (h0 = 0 so Whh2 drops; c_prev = 0 so the
// f-gate is irrelevant). One thread per (n,k). Writes tree initial state.
// ---------------------------------------------------------------------------
__global__ __launch_bounds__(256) void k_lstm2(
    const float* __restrict__ outbuf, const float* __restrict__ Wih2,
    const float* __restrict__ b2, float* __restrict__ hidA,
    float* __restrict__ cidA)
{
  const int idx = blockIdx.x * 256 + threadIdx.x;  // [0,16384)
  const int n = idx >> 7, k = idx & 127;
  const float* x = outbuf + (15 * 128 + n) * 88;
  float ai = b2[k];
  float ag = b2[256 + k];
  float ao = b2[384 + k];
  for (int f = 0; f < 88; ++f) {
    float xv = x[f];
    ai = fmaf(xv, Wih2[f * 512 + k], ai);
    ag = fmaf(xv, Wih2[f * 512 + 256 + k], ag);
    ao = fmaf(xv, Wih2[f * 512 + 384 + k], ao);
  }
  float c0 = sigf(ai) * tanhfast(ag);
  float h0 = sigf(ao) * tanhfast(c0);
  hidA[idx] = h0;
  cidA[idx] = c0;
}

// ---------------------------------------------------------------------------
// K_prep: bx==0: base_all[t][k] = out[t][n=0] @ Win + bin_ (t<15).
// bx 1..10: LDS-tiled transpose of matrix m=bx-1 (Wlh g<5, then Wrh):
// WT[m][k][h] = W[m][h][k].
// ---------------------------------------------------------------------------
__global__ __launch_bounds__(256) void k_prep(
    const float* __restrict__ outbuf, const float* __restrict__ Win,
    const float* __restrict__ binb, const float* __restrict__ Wlh,
    const float* __restrict__ Wrh, float* __restrict__ base_all,
    float* __restrict__ WT)
{
  const int bx = blockIdx.x, tid = threadIdx.x;
  if (bx == 0) {
    for (int idx = tid; idx < 15 * 128; idx += 256) {
      int t = idx >> 7, k = idx & 127;
      float a = binb[k];
      const float* x = outbuf + (t * 128) * 88;  // row n=0 of level t
      for (int f = 0; f < 88; ++f) a = fmaf(x[f], Win[f * 128 + k], a);
      base_all[idx] = a;
    }
  } else {
    __shared__ float tile[32][33];
    const int m = bx - 1;                 // 0..9 = side*5+g
    const int side = m / 5, g = m - side * 5;
    const float* src = (side ? Wrh : Wlh) + g * 16384;
    float* dst = WT + m * 16384;
    const int i = tid >> 5, jj = tid & 31;  // i in [0,8)
    for (int tt = 0; tt < 16; ++tt) {
      const int ti = tt >> 2, tj = tt & 3;
#pragma unroll
      for (int q = 0; q < 4; ++q)
        tile[i + q * 8][jj] = src[(ti * 32 + i + q * 8) * 128 + tj * 32 + jj];
      __syncthreads();
#pragma unroll
      for (int q = 0; q < 4; ++q)
        dst[(tj * 32 + i + q * 8) * 128 + ti * 32 + jj] = tile[jj][i + q * 8];
      __syncthreads();
    }
  }
}

// ---------------------------------------------------------------------------
// K_tree: one TreeLSTM level, a=0 slice only. grid 128 = 16 k-blocks x 8
// n-blocks, 256 threads. Thread (pr=tid>>1, side=tid&1): 5 gate dots for its
// side over h=128; LDS combine; tid<128 does gates + state update.
// ---------------------------------------------------------------------------
__global__ __launch_bounds__(256, 1) void k_tree(
    const int* __restrict__ mapping, const float* __restrict__ WT,
    const float* __restrict__ base_all, const float* __restrict__ blh,
    const float* __restrict__ brh, const float* __restrict__ hid_c,
    const float* __restrict__ cid_c, float* __restrict__ hid_n,
    float* __restrict__ cid_n, int t)
{
  __shared__ float wS[10][8][132];   // (side*5+g, k', h) padded stride
  __shared__ float rowS[32][132];    // (n'*2+side, h) gathered child h rows
  __shared__ float pS[128][10];      // partial dots
  const int tid = threadIdx.x, bx = blockIdx.x;
  const int k0 = (bx & 15) * 8, n0 = (bx >> 4) * 16;

  for (int idx = tid; idx < 10 * 8 * 128; idx += 256) {
    int h = idx & 127, kp = (idx >> 7) & 7, sg = idx >> 10;
    wS[sg][kp][h] = WT[sg * 16384 + (k0 + kp) * 128 + h];
  }
  for (int idx = tid; idx < 4096; idx += 256) {
    int row = idx >> 7, h = idx & 127;  // row = n'*2 + side
    int np_ = row >> 1, side = row & 1;
    int j = mapping[(t * 128 + n0 + np_) * 2 + side];
    rowS[row][h] = (j > 0) ? hid_c[(j - 1) * 128 + h] : 0.0f;
  }
  __syncthreads();

  {
    const int pr = tid >> 1, side = tid & 1;
    const int np_ = pr >> 3, kp = pr & 7;
    const int rrow = np_ * 2 + side;
    float acc[5] = {0.f, 0.f, 0.f, 0.f, 0.f};
    for (int h = 0; h < 128; h += 8) {
      float4 r0 = *(const float4*)&rowS[rrow][h];
      float4 r1 = *(const float4*)&rowS[rrow][h + 4];
#pragma unroll
      for (int g = 0; g < 5; ++g) {
        float4 w0 = *(const float4*)&wS[side * 5 + g][kp][h];
        float4 w1 = *(const float4*)&wS[side * 5 + g][kp][h + 4];
        acc[g] = fmaf(r0.x, w0.x, acc[g]);
        acc[g] = fmaf(r0.y, w0.y, acc[g]);
        acc[g] = fmaf(r0.z, w0.z, acc[g]);
        acc[g] = fmaf(r0.w, w0.w, acc[g]);
        acc[g] = fmaf(r1.x, w1.x, acc[g]);
        acc[g] = fmaf(r1.y, w1.y, acc[g]);
        acc[g] = fmaf(r1.z, w1.z, acc[g]);
        acc[g] = fmaf(r1.w, w1.w, acc[g]);
      }
    }
#pragma unroll
    for (int g = 0; g < 5; ++g) pS[pr][side * 5 + g] = acc[g];
  }
  __syncthreads();
  if (tid < 128) {
    const int np_ = tid >> 3, kp = tid & 7;
    const int n = n0 + np_, k = k0 + kp;
    const float base = base_all[t * 128 + k];
    float pre[5];
#pragma unroll
    for (int g = 0; g < 5; ++g)
      pre[g] = pS[tid][g] + pS[tid][5 + g] + base +
               blh[g * 128 + k] + brh[g * 128 + k];
    int jl = mapping[(t * 128 + n) * 2 + 0];
    int jr = mapping[(t * 128 + n) * 2 + 1];
    float lc = (jl > 0) ? cid_c[(jl - 1) * 128 + k] : 0.0f;
    float rc = (jr > 0) ? cid_c[(jr - 1) * 128 + k] : 0.0f;
    float i_ = sigf(pre[0]);
    float lf = sigf(pre[1]);
    float rf = sigf(pre[2]);
    float u_ = tanhfast(pre[3]);
    float o_ = sigf(pre[4]);
    float c = i_ * u_ + lf * lc + rf * rc;
    hid_n[n * 128 + k] = o_ * tanhfast(c);
    cid_n[n * 128 + k] = c;
  }
}

// ---------------------------------------------------------------------------
// K_head: BN2 -> relu(@Wt1) -> BN3 -> relu(@Wt2) -> sigmoid(@Wo). One block,
// 512 threads. bf16 LDS intermediates (t1,t2); t4(f32) aliases t1's pool.
// Output written as FLOAT32 (reference output dtype).
// ---------------------------------------------------------------------------
__global__ __launch_bounds__(512) void k_head(
    const float* __restrict__ hid, const float* __restrict__ g2,
    const float* __restrict__ be2, const float* __restrict__ Wt1,
    const float* __restrict__ bt1, const float* __restrict__ g3,
    const float* __restrict__ be3, const float* __restrict__ Wt2,
    const float* __restrict__ bt2, const float* __restrict__ Wo,
    const float* __restrict__ bo, float* __restrict__ dout)
{
  __shared__ __align__(16) unsigned char pool[32768 + 16384];
  __hip_bfloat16 (*t1s)[128] = (__hip_bfloat16(*)[128])pool;          // 32KB
  __hip_bfloat16 (*t2s)[64]  = (__hip_bfloat16(*)[64])(pool + 32768); // 16KB
  float (*t4s)[64] = (float(*)[64])pool;      // reuses t1 space (dead by then)
  __shared__ float red[8][128];
  __shared__ float av[128], bv[128];
  const int tid = threadIdx.x;

  // BN2 stats over hid (128 rows x 128 cols)
  {
    int k = tid & 127, q = tid >> 7;  // q in [0,4)
    float s = 0.f, s2 = 0.f;
    for (int r = q * 32; r < q * 32 + 32; ++r) {
      float v = hid[r * 128 + k];
      s += v; s2 += v * v;
    }
    red[q][k] = s;
    red[4 + q][k] = s2;
  }
  __syncthreads();
  if (tid < 128) {
    float s = red[0][tid] + red[1][tid] + red[2][tid] + red[3][tid];
    float s2 = red[4][tid] + red[5][tid] + red[6][tid] + red[7][tid];
    float m = s * (1.0f / 128.0f);
    float var = s2 * (1.0f / 128.0f) - m * m;
    float rstd = rsqrtf(var + 1e-5f);
    float gg = g2[tid];
    av[tid] = rstd * gg;
    bv[tid] = be2[tid] - m * rstd * gg;
  }
  __syncthreads();
  for (int idx = tid; idx < 16384; idx += 512) {
    int n = idx >> 7, k = idx & 127;
    t1s[n][k] = __float2bfloat16(hid[idx] * av[k] + bv[k]);
  }
  __syncthreads();
  // t2 = relu(t1 @ Wt1 + bt1): thread (j = tid&63, ng = tid>>6) -> 16 rows
  {
    const int j = tid & 63, ng = tid >> 6;
    float a[16];
#pragma unroll
    for (int r = 0; r < 16; ++r) a[r] = bt1[j];
    for (int k8 = 0; k8 < 128; k8 += 8) {
      float wv[8];
#pragma unroll
      for (int q = 0; q < 8; ++q) wv[q] = Wt1[(k8 + q) * 64 + j];
#pragma unroll
      for (int r = 0; r < 16; ++r) {
        const __hip_bfloat16* row = &t1s[ng * 16 + r][k8];
#pragma unroll
        for (int q = 0; q < 8; ++q)
          a[r] = fmaf(__bfloat162float(row[q]), wv[q], a[r]);
      }
    }
#pragma unroll
    for (int r = 0; r < 16; ++r)
      t2s[ng * 16 + r][j] = __float2bfloat16(fmaxf(a[r], 0.0f));
  }
  __syncthreads();
  // BN3 stats over t2 (128 rows x 64 cols)
  {
    int j = tid & 63, q = tid >> 6;  // q in [0,8)
    float s = 0.f, s2 = 0.f;
    for (int r = q * 16; r < q * 16 + 16; ++r) {
      float v = __bfloat162float(t2s[r][j]);
      s += v; s2 += v * v;
    }
    red[q][j] = s;
    red[q][64 + j] = s2;
  }
  __syncthreads();
  if (tid < 64) {
    float s = 0.f, s2 = 0.f;
#pragma unroll
    for (int q = 0; q < 8; ++q) { s += red[q][tid]; s2 += red[q][64 + tid]; }
    float m = s * (1.0f / 128.0f);
    float var = s2 * (1.0f / 128.0f) - m * m;
    float rstd = rsqrtf(var + 1e-5f);
    float gg = g3[tid];
    av[tid] = rstd * gg;
    bv[tid] = be3[tid] - m * rstd * gg;
  }
  __syncthreads();
  // t4 = relu(bn3(t2) @ Wt2 + bt2); writes alias old t1 pool (t1 dead)
  {
    const int j2 = tid & 63, ng = tid >> 6;
    float a[16];
#pragma unroll
    for (int r = 0; r < 16; ++r) a[r] = bt2[j2];
    for (int jj = 0; jj < 64; ++jj) {
      float w = Wt2[jj * 64 + j2];
      float aj = av[jj], bj = bv[jj];
#pragma unroll
      for (int r = 0; r < 16; ++r) {
        float x = __bfloat162float(t2s[ng * 16 + r][jj]) * aj + bj;
        a[r] = fmaf(x, w, a[r]);
      }
    }
    __syncthreads();   // t1s reads long done; order t4 writes after
#pragma unroll
    for (int r = 0; r < 16; ++r) t4s[ng * 16 + r][j2] = fmaxf(a[r], 0.0f);
  }
  __syncthreads();
  if (tid < 128) {
    float a = bo[0];
    for (int j = 0; j < 64; ++j) a = fmaf(t4s[tid][j], Wo[j], a);
    dout[tid] = sigf(a);   // FLOAT32 output
  }
}

// ---------------------------------------------------------------------------
extern "C" void kernel_launch(void* const* d_in, const int* in_sizes, int n_in,
                              void* d_out, int out_size, void* d_ws,
                              size_t ws_size, hipStream_t stream)
{
  (void)in_sizes; (void)n_in; (void)out_size; (void)ws_size;
  const float* ops   = (const float*)d_in[0];
  const float* extra = (const float*)d_in[1];
  const float* card  = (const float*)d_in[2];
  const float* cond1 = (const float*)d_in[3];
  const float* cond2 = (const float*)d_in[4];
  const int* mapping = (const int*)d_in[5];
  const float* Wih1 = (const float*)d_in[6];
  const float* Whh1 = (const float*)d_in[7];
  const float* b1   = (const float*)d_in[8];
  const float* Wc   = (const float*)d_in[9];
  const float* bc   = (const float*)d_in[10];
  const float* g1   = (const float*)d_in[11];
  const float* be1  = (const float*)d_in[12];
  const float* Wih2 = (const float*)d_in[13];
  // d_in[14] = Whh2: unused (h0 = 0 in the single-step LSTM2)
  const float* b2   = (const float*)d_in[15];
  const float* Win  = (const float*)d_in[16];
  const float* binb = (const float*)d_in[17];
  const float* Wlh  = (const float*)d_in[18];
  const float* blh  = (const float*)d_in[19];
  const float* Wrh  = (const float*)d_in[20];
  const float* brh  = (const float*)d_in[21];
  const float* g2   = (const float*)d_in[22];
  const float* be2  = (const float*)d_in[23];
  const float* Wt1  = (const float*)d_in[24];
  const float* bt1  = (const float*)d_in[25];
  const float* g3   = (const float*)d_in[26];
  const float* be3  = (const float*)d_in[27];
  const float* Wt2  = (const float*)d_in[28];
  const float* bt2  = (const float*)d_in[29];
  const float* Wo   = (const float*)d_in[30];
  const float* bo   = (const float*)d_in[31];

  char* ws = (char*)d_ws;
  float* gsums    = (float*)(ws + 0);        // 128 f32
  float* lo_raw   = (float*)(ws + 512);      // 2048x64 f32
  float* outbuf   = (float*)(ws + 524800);   // 2048x88 f32
  float* base_all = (float*)(ws + 1245696);  // 15x128 f32
  float* WT       = (float*)(ws + 1253376);  // 10x128x128 f32 (transposed)
  float* hidA     = (float*)(ws + 1908736);  // 128x128 f32 x4 (ping-pong)
  float* hidB     = hidA + 16384;
  float* cidA     = hidB + 16384;
  float* cidB     = cidA + 16384;

  hipMemsetAsync(gsums, 0, 512, stream);
  k_lstm1<<<dim3(256), dim3(512), 0, stream>>>(
      cond1, cond2, Wih1, Whh1, b1, Wc, bc, lo_raw, gsums);
  k_buildout<<<dim3(8), dim3(256), 0, stream>>>(
      ops, extra, card, g1, be1, gsums, lo_raw, outbuf);
  k_lstm2<<<dim3(64), dim3(256), 0, stream>>>(outbuf, Wih2, b2, hidA, cidA);
  k_prep<<<dim3(11), dim3(256), 0, stream>>>(
      outbuf, Win, binb, Wlh, Wrh, base_all, WT);

  float* hc[2] = {hidA, hidB};
  float* cc[2] = {cidA, cidB};
  for (int s = 0; s < 15; ++s) {
    int t = 14 - s;           // levels processed in reverse
    int cur = s & 1, nxt = cur ^ 1;
    k_tree<<<dim3(128), dim3(256), 0, stream>>>(
        mapping, WT, base_all, blh, brh,
        hc[cur], cc[cur], hc[nxt], cc[nxt], t);
  }
  // 15 steps (odd count): final state sits in buffer 1
  k_head<<<dim3(1), dim3(512), 0, stream>>>(
      hc[1], g2, be2, Wt1, bt1, g3, be3, Wt2, bt2, Wo, bo,
      (float*)d_out);
}